// Round 3
// baseline (217.106 us; speedup 1.0000x reference)
//
#include <hip/hip_runtime.h>
#include <hip/hip_bf16.h>

// MoE: N=4096 tokens, D=512, H=2048, E=8 experts, top-2.
// Round 11: counted-vmcnt double-buffer pipeline in both GEMMs.
// Round-9 post-mortem (corrected): its dbuf failed because __syncthreads()
// emits s_waitcnt vmcnt(0) before s_barrier -- the prefetch was drained at
// the first barrier and never overlapped. Fix per the m201/8-phase template:
// raw s_barrier + inline-asm counted vmcnt(N) so next-tile loads stay in
// flight across the barrier (N = loads of the in-flight prefetch; drain to 0
// only on the last K-step). sched_barrier(0) pins ordering.
//  - gemm1: 128x128 tile, dbuf 66KB LDS (2 blocks/CU), vmcnt(8).
//  - gemm2: 64x128 tile, dbuf 49KB LDS (3 blocks/CU), vmcnt(6).
//  - XCD clustering, XOR swizzle (0 conflicts), tb-prefix tables, KSPLIT=2,
//    O-aliasing-W1t, fallback path: unchanged from round 10.

#define N_TOK 4096
#define DIM   512
#define HID   2048
#define NEXP  8
#define TOTSLOT (2 * N_TOK)
#define M1TILE 72     // max 128-slot tiles (gemm1)
#define M2TILE 144    // max 64-slot tiles  (gemm2)

typedef __attribute__((ext_vector_type(8))) short short8;
typedef __attribute__((ext_vector_type(4))) float f32x4;

static __device__ __forceinline__ unsigned short f2bf(float f) {
    __hip_bfloat16 b = __float2bfloat16(f);
    return *reinterpret_cast<unsigned short*>(&b);
}
static __device__ __forceinline__ float bf2f(unsigned short u) {
    return __uint_as_float((unsigned)u << 16);
}

static __device__ __forceinline__ void load16_to_lds(const void* g, void* l) {
    __builtin_amdgcn_global_load_lds(
        (const __attribute__((address_space(1))) unsigned int*)g,
        (__attribute__((address_space(3))) unsigned int*)l, 16, 0, 0);
}

// ---------------------------------------------------------------- gating ----
__global__ __launch_bounds__(256) void gating_kernel(
    const float* __restrict__ x, const float* __restrict__ Wg,
    const float* __restrict__ bg,
    int* __restrict__ cnt, int* __restrict__ te, float* __restrict__ tw,
    float* __restrict__ usage, unsigned short* __restrict__ Xb)
{
    __shared__ int   lcnt[NEXP];
    __shared__ float lus[NEXP];
    int tid = threadIdx.x;
    if (tid < NEXP) { lcnt[tid] = 0; lus[tid] = 0.f; }
    __syncthreads();

    int wave = tid >> 6;
    int lane = tid & 63;

    for (int t = 0; t < 4; ++t) {
        int n = blockIdx.x * 16 + wave * 4 + t;

        float acc[NEXP];
#pragma unroll
        for (int e = 0; e < NEXP; ++e) acc[e] = 0.f;

#pragma unroll
        for (int it = 0; it < DIM / 64; ++it) {
            int d = it * 64 + lane;
            float xv = x[n * DIM + d];
            Xb[n * DIM + d] = f2bf(xv);
            float4 wa = *(const float4*)&Wg[d * NEXP];
            float4 wb = *(const float4*)&Wg[d * NEXP + 4];
            acc[0] += xv * wa.x; acc[1] += xv * wa.y;
            acc[2] += xv * wa.z; acc[3] += xv * wa.w;
            acc[4] += xv * wb.x; acc[5] += xv * wb.y;
            acc[6] += xv * wb.z; acc[7] += xv * wb.w;
        }
#pragma unroll
        for (int m = 32; m >= 1; m >>= 1) {
#pragma unroll
            for (int e = 0; e < NEXP; ++e)
                acc[e] += __shfl_xor(acc[e], m, 64);
        }
        if (lane == 0) {
            float l[NEXP];
#pragma unroll
            for (int e = 0; e < NEXP; ++e) l[e] = acc[e] + bg[e];
            int i0 = 0;
#pragma unroll
            for (int e = 1; e < NEXP; ++e) if (l[e] > l[i0]) i0 = e;
            int i1 = (i0 == 0) ? 1 : 0;
#pragma unroll
            for (int e = 0; e < NEXP; ++e)
                if (e != i0 && l[e] > l[i1]) i1 = e;
            float w0 = 1.f / (1.f + expf(l[i1] - l[i0]));
            float w1 = 1.f - w0;
            te[n * 2] = i0; te[n * 2 + 1] = i1;
            tw[n * 2] = w0; tw[n * 2 + 1] = w1;
            atomicAdd(&lcnt[i0], 1);
            atomicAdd(&lcnt[i1], 1);
            atomicAdd(&lus[i0], w0);
            atomicAdd(&lus[i1], w1);
        }
    }
    __syncthreads();
    if (tid < NEXP) {
        if (lcnt[tid]) atomicAdd(&cnt[tid], lcnt[tid]);
        if (lus[tid] != 0.f) atomicAdd(&usage[tid], lus[tid]);
    }
}

// tb128[e]/tb64[e]: first tile index of expert e at 128/64-slot granularity.
__global__ void prefix_kernel(const int* __restrict__ cnt,
                              int* __restrict__ offs, int* __restrict__ fill,
                              int* __restrict__ tb128, int* __restrict__ tb64,
                              int* __restrict__ ntile)
{
    if (threadIdx.x == 0) {
        int s = 0, a = 0, b = 0;
        for (int e = 0; e < NEXP; ++e) {
            offs[e] = s; s += cnt[e];
            tb128[e] = a; a += (cnt[e] + 127) >> 7;
            tb64[e]  = b; b += (cnt[e] + 63) >> 6;
        }
        tb128[NEXP] = a; tb64[NEXP] = b;
        ntile[0] = a; ntile[1] = b;
    }
    if (threadIdx.x < NEXP) fill[threadIdx.x] = 0;
}

__global__ __launch_bounds__(256) void scatter_kernel(
    int* __restrict__ te, const float* __restrict__ tw,
    const int* __restrict__ offs, int* __restrict__ fill,
    int* __restrict__ btok, float* __restrict__ bwt)
{
    __shared__ int lcnt[NEXP];
    __shared__ int gbase[NEXP];
    int tid = threadIdx.x;
    if (tid < NEXP) lcnt[tid] = 0;
    __syncthreads();
    int n = blockIdx.x * 256 + tid;
    int e0 = te[n * 2], e1 = te[n * 2 + 1];
    int l0 = atomicAdd(&lcnt[e0], 1);
    int l1 = atomicAdd(&lcnt[e1], 1);
    __syncthreads();
    if (tid < NEXP) gbase[tid] = atomicAdd(&fill[tid], lcnt[tid]);
    __syncthreads();
    int s0 = offs[e0] + gbase[e0] + l0;
    int s1 = offs[e1] + gbase[e1] + l1;
    btok[s0] = n; bwt[s0] = tw[n * 2];
    btok[s1] = n; bwt[s1] = tw[n * 2 + 1];
    te[n * 2] = s0; te[n * 2 + 1] = s1;   // slot map for combine
}

// in: [E][R][C] fp32  ->  out: [E][C][R] bf16
__global__ __launch_bounds__(256) void transpose_cvt_kernel(
    const float* __restrict__ in, unsigned short* __restrict__ out,
    int R, int C)
{
    __shared__ unsigned short tile[64][65];
    int e = blockIdx.z;
    const float* src = in + (size_t)e * R * C;
    unsigned short* dst = out + (size_t)e * R * C;
    int r0 = blockIdx.x * 64, c0 = blockIdx.y * 64;
    int tid = threadIdx.x;
    int rr = tid >> 2, cb = (tid & 3) * 16;
#pragma unroll
    for (int i = 0; i < 4; ++i) {
        float4 v = *(const float4*)&src[(size_t)(r0 + rr) * C + c0 + cb + i * 4];
        tile[rr][cb + i * 4 + 0] = f2bf(v.x);
        tile[rr][cb + i * 4 + 1] = f2bf(v.y);
        tile[rr][cb + i * 4 + 2] = f2bf(v.z);
        tile[rr][cb + i * 4 + 3] = f2bf(v.w);
    }
    __syncthreads();
#pragma unroll
    for (int i = 0; i < 4; ++i) {
        ushort4 u;
        u.x = tile[cb + i * 4 + 0][rr];
        u.y = tile[cb + i * 4 + 1][rr];
        u.z = tile[cb + i * 4 + 2][rr];
        u.w = tile[cb + i * 4 + 3][rr];
        *(ushort4*)&dst[(size_t)(c0 + rr) * R + r0 + cb + i * 4] = u;
    }
}

// ------------------------------------------------------------- MFMA GEMM ----
// LDS: rows x 64 bf16 per buffer, chunk c of row R at physical c^(R&7)
// (0 bank conflicts). Counted-vmcnt dbuf: stage(next) -> vmcnt(cur-done) ->
// raw barrier -> MFMA(cur) -> raw barrier. Prefetch stays in flight.

// gemm1: 128 tokens x 128 h per block. grid (72, 16).
__global__ __launch_bounds__(256) void gemm1_kernel(
    const unsigned short* __restrict__ Xb, const unsigned short* __restrict__ W1t,
    const float* __restrict__ b1, const int* __restrict__ cnt,
    const int* __restrict__ offs, const int* __restrict__ btok,
    const int* __restrict__ tb128, const int* __restrict__ ntile,
    unsigned short* __restrict__ H1)
{
    __shared__ __align__(16) unsigned short Ws[2][128 * 64];
    __shared__ __align__(16) unsigned short Xs[2][128 * 64];
    __shared__ int tok_s[128];

    int bx = blockIdx.x;
    int ti = (bx & 7) * (M1TILE / 8) + (bx >> 3);
    if (ti >= ntile[0]) return;
    int e = 0;
#pragma unroll
    for (int k = 1; k < NEXP; ++k) if (ti >= tb128[k]) e = k;
    int tt = ti - tb128[e];
    int ht = blockIdx.y;
    int cn = cnt[e];
    int off_e = offs[e];
    int tid = threadIdx.x;

    if (tid < 128) {
        int lr = tt * 128 + tid;
        tok_s[tid] = (lr < cn) ? btok[off_e + lr] : 0;
    }
    __syncthreads();   // tok_s read by staging

    int wave = tid >> 6, lane = tid & 63;
    int mbase = (wave >> 1) * 64, nbase = (wave & 1) * 64;
    int quad = lane >> 4, lcol = lane & 15;
    f32x4 acc[4][4];
#pragma unroll
    for (int mi = 0; mi < 4; ++mi)
#pragma unroll
        for (int ni = 0; ni < 4; ++ni)
            acc[mi][ni] = (f32x4){0.f, 0.f, 0.f, 0.f};

    int Rb = tid >> 3, pc = tid & 7;
    const unsigned short* Wsrc = W1t + ((size_t)e * HID + ht * 128) * DIM;

    auto stage = [&](int buf, int k0) {
#pragma unroll
        for (int p = 0; p < 4; ++p) {
            int R = Rb + p * 32;
            int c = pc ^ (R & 7);
            load16_to_lds(&Wsrc[(size_t)R * DIM + k0 + c * 8], &Ws[buf][R * 64 + pc * 8]);
            load16_to_lds(&Xb[(size_t)tok_s[R] * DIM + k0 + c * 8], &Xs[buf][R * 64 + pc * 8]);
        }
    };

    stage(0, 0);                       // 8 loads in flight

    const int NT = DIM / 64;           // 8
    for (int t = 0; t < NT; ++t) {
        int cur = t & 1;
        if (t + 1 < NT) {
            stage(cur ^ 1, (t + 1) * 64);              // +8 loads (<=16 out)
            asm volatile("s_waitcnt vmcnt(8)" ::: "memory");  // cur's 8 done
        } else {
            asm volatile("s_waitcnt vmcnt(0)" ::: "memory");
        }
        __builtin_amdgcn_s_barrier();                  // no implicit drain
        __builtin_amdgcn_sched_barrier(0);
#pragma unroll
        for (int h = 0; h < 2; ++h) {
            int cs = ((h * 4 + quad) ^ (lcol & 7)) * 8;
            short8 a[4], b[4];
#pragma unroll
            for (int i = 0; i < 4; ++i) {
                a[i] = *(const short8*)&Ws[cur][(mbase + i * 16 + lcol) * 64 + cs];
                b[i] = *(const short8*)&Xs[cur][(nbase + i * 16 + lcol) * 64 + cs];
            }
#pragma unroll
            for (int mi = 0; mi < 4; ++mi)
#pragma unroll
                for (int ni = 0; ni < 4; ++ni)
                    acc[mi][ni] = __builtin_amdgcn_mfma_f32_16x16x32_bf16(
                        a[mi], b[ni], acc[mi][ni], 0, 0, 0);
        }
        __builtin_amdgcn_sched_barrier(0);
        __builtin_amdgcn_s_barrier();                  // cur reads done
    }

    float4 bv[4];
#pragma unroll
    for (int mi = 0; mi < 4; ++mi)
        bv[mi] = *(const float4*)&b1[e * HID + ht * 128 + mbase + mi * 16 + quad * 4];
#pragma unroll
    for (int ni = 0; ni < 4; ++ni) {
        int tn = tt * 128 + nbase + ni * 16 + lcol;
        if (tn >= cn) continue;
        size_t srow = (size_t)(off_e + tn) * HID + ht * 128;
#pragma unroll
        for (int mi = 0; mi < 4; ++mi) {
            int hh = mbase + mi * 16 + quad * 4;
            ushort4 u;
            u.x = f2bf(acc[mi][ni][0] + bv[mi].x);
            u.y = f2bf(acc[mi][ni][1] + bv[mi].y);
            u.z = f2bf(acc[mi][ni][2] + bv[mi].z);
            u.w = f2bf(acc[mi][ni][3] + bv[mi].w);
            *(ushort4*)&H1[srow + hh] = u;
        }
    }
}

#define KSPLIT 2
#define KCH (HID / KSPLIT)

// gemm2: 64 slots x 128 d per block. grid (144, 4, 2).
__global__ __launch_bounds__(256) void gemm2_kernel(
    const unsigned short* __restrict__ H1, const unsigned short* __restrict__ W2t,
    const float* __restrict__ b2, const int* __restrict__ cnt,
    const int* __restrict__ offs, const float* __restrict__ bwt,
    const int* __restrict__ tb64, const int* __restrict__ ntile,
    unsigned short* __restrict__ O)
{
    __shared__ __align__(16) unsigned short Ws[2][128 * 64];   // d rows
    __shared__ __align__(16) unsigned short Hs[2][64 * 64];    // slot rows
    __shared__ float wt_s[64];

    int bx = blockIdx.x;
    int ti = (bx & 7) * (M2TILE / 8) + (bx >> 3);
    if (ti >= ntile[1]) return;
    int e = 0;
#pragma unroll
    for (int k = 1; k < NEXP; ++k) if (ti >= tb64[k]) e = k;
    int tt = ti - tb64[e];
    int dt = blockIdx.y, kz = blockIdx.z;
    int cn = cnt[e];
    int off_e = offs[e];
    int sb = off_e + tt * 64;
    int tid = threadIdx.x;

    if (tid < 64) {
        int lr = tt * 64 + tid;
        wt_s[tid] = (lr < cn) ? bwt[off_e + lr] : 0.f;
    }

    int wave = tid >> 6, lane = tid & 63;
    int nbase = wave * 32;                 // d-offset of this wave within 128
    int quad = lane >> 4, lcol = lane & 15;
    f32x4 acc[4][2];
#pragma unroll
    for (int mi = 0; mi < 4; ++mi)
#pragma unroll
        for (int ni = 0; ni < 2; ++ni)
            acc[mi][ni] = (f32x4){0.f, 0.f, 0.f, 0.f};

    int Rb = tid >> 3, pc = tid & 7;
    const unsigned short* Wsrc = W2t + ((size_t)e * DIM + dt * 128) * HID;

    auto stage = [&](int buf, int k0) {
#pragma unroll
        for (int p = 0; p < 4; ++p) {      // Ws: 128 d-rows
            int R = Rb + p * 32;
            int c = pc ^ (R & 7);
            load16_to_lds(&Wsrc[(size_t)R * HID + k0 + c * 8], &Ws[buf][R * 64 + pc * 8]);
        }
#pragma unroll
        for (int p = 0; p < 2; ++p) {      // Hs: 64 slot-rows
            int R = Rb + p * 32;
            int c = pc ^ (R & 7);
            int sr = sb + R; if (sr > TOTSLOT - 1) sr = TOTSLOT - 1;
            load16_to_lds(&H1[(size_t)sr * HID + k0 + c * 8], &Hs[buf][R * 64 + pc * 8]);
        }
    };

    stage(0, kz * KCH);                    // 6 loads in flight

    const int NT = KCH / 64;               // 16
    for (int t = 0; t < NT; ++t) {
        int cur = t & 1;
        if (t + 1 < NT) {
            stage(cur ^ 1, kz * KCH + (t + 1) * 64);   // +6 loads (<=12 out)
            asm volatile("s_waitcnt vmcnt(6)" ::: "memory");  // cur's 6 done
        } else {
            asm volatile("s_waitcnt vmcnt(0)" ::: "memory");
        }
        __builtin_amdgcn_s_barrier();
        __builtin_amdgcn_sched_barrier(0);
#pragma unroll
        for (int h = 0; h < 2; ++h) {
            int cs = ((h * 4 + quad) ^ (lcol & 7)) * 8;
            short8 a[4], b[2];
#pragma unroll
            for (int i = 0; i < 4; ++i)
                a[i] = *(const short8*)&Hs[cur][(i * 16 + lcol) * 64 + cs];          // A = slots
#pragma unroll
            for (int i = 0; i < 2; ++i)
                b[i] = *(const short8*)&Ws[cur][(nbase + i * 16 + lcol) * 64 + cs];  // B = d
#pragma unroll
            for (int mi = 0; mi < 4; ++mi)
#pragma unroll
                for (int ni = 0; ni < 2; ++ni)
                    acc[mi][ni] = __builtin_amdgcn_mfma_f32_16x16x32_bf16(
                        a[mi], b[ni], acc[mi][ni], 0, 0, 0);
        }
        __builtin_amdgcn_sched_barrier(0);
        __builtin_amdgcn_s_barrier();
    }

    unsigned short* Oe = O + ((size_t)kz * TOTSLOT + sb) * DIM + dt * 128;
#pragma unroll
    for (int ni = 0; ni < 2; ++ni) {
        int dl = nbase + ni * 16 + lcol;
        float bv = (kz == 0) ? b2[e * DIM + dt * 128 + dl] : 0.f;
#pragma unroll
        for (int mi = 0; mi < 4; ++mi) {
            int rl = mi * 16 + quad * 4;
#pragma unroll
            for (int r = 0; r < 4; ++r) {
                int sl = rl + r;
                if (tt * 64 + sl < cn)
                    Oe[(size_t)sl * DIM + dl] = f2bf(wt_s[sl] * (acc[mi][ni][r] + bv));
            }
        }
    }
}

// out[n][d] = sum of 4 partial rows: O[kz][slot][d].
__global__ __launch_bounds__(256) void combine_kernel(
    const unsigned short* __restrict__ O, const int* __restrict__ sidx,
    float* __restrict__ out)
{
    int tid = threadIdx.x;
    int n = blockIdx.x * 2 + (tid >> 7);
    int dd = (tid & 127) * 4;
    int s0 = sidx[n * 2], s1 = sidx[n * 2 + 1];
    ushort4 a = *(const ushort4*)&O[(size_t)s0 * DIM + dd];
    ushort4 b = *(const ushort4*)&O[((size_t)TOTSLOT + s0) * DIM + dd];
    ushort4 c = *(const ushort4*)&O[(size_t)s1 * DIM + dd];
    ushort4 d = *(const ushort4*)&O[((size_t)TOTSLOT + s1) * DIM + dd];
    float4 o;
    o.x = bf2f(a.x) + bf2f(b.x) + bf2f(c.x) + bf2f(d.x);
    o.y = bf2f(a.y) + bf2f(b.y) + bf2f(c.y) + bf2f(d.y);
    o.z = bf2f(a.z) + bf2f(b.z) + bf2f(c.z) + bf2f(d.z);
    o.w = bf2f(a.w) + bf2f(b.w) + bf2f(c.w) + bf2f(d.w);
    *(float4*)&out[(size_t)n * DIM + dd] = o;
}

// ------------------------------------------------- round-1 fp32 fallback ----
#define TN 16
#define HC 256
#define NCHUNK (HID / HC)

__global__ __launch_bounds__(256) void gating_fb_kernel(
    const float* __restrict__ x, const float* __restrict__ Wg,
    const float* __restrict__ bg,
    int* __restrict__ cnt, int* __restrict__ btok, float* __restrict__ bwt,
    float* __restrict__ usage)
{
    int wave = threadIdx.x >> 6;
    int lane = threadIdx.x & 63;
    int n = blockIdx.x * 4 + wave;
    float acc[NEXP];
#pragma unroll
    for (int e = 0; e < NEXP; ++e) acc[e] = 0.f;
    for (int d = lane; d < DIM; d += 64) {
        float xv = x[n * DIM + d];
        float4 wa = *(const float4*)&Wg[d * NEXP];
        float4 wb = *(const float4*)&Wg[d * NEXP + 4];
        acc[0] += xv * wa.x; acc[1] += xv * wa.y;
        acc[2] += xv * wa.z; acc[3] += xv * wa.w;
        acc[4] += xv * wb.x; acc[5] += xv * wb.y;
        acc[6] += xv * wb.z; acc[7] += xv * wb.w;
    }
#pragma unroll
    for (int m = 32; m >= 1; m >>= 1)
#pragma unroll
        for (int e = 0; e < NEXP; ++e)
            acc[e] += __shfl_xor(acc[e], m, 64);
    if (lane == 0) {
        float l[NEXP];
#pragma unroll
        for (int e = 0; e < NEXP; ++e) l[e] = acc[e] + bg[e];
        int i0 = 0;
#pragma unroll
        for (int e = 1; e < NEXP; ++e) if (l[e] > l[i0]) i0 = e;
        int i1 = (i0 == 0) ? 1 : 0;
#pragma unroll
        for (int e = 0; e < NEXP; ++e)
            if (e != i0 && l[e] > l[i1]) i1 = e;
        float w0 = 1.f / (1.f + expf(l[i1] - l[i0]));
        float w1 = 1.f - w0;
        int p0 = atomicAdd(&cnt[i0], 1);
        btok[i0 * N_TOK + p0] = n; bwt[i0 * N_TOK + p0] = w0;
        int p1 = atomicAdd(&cnt[i1], 1);
        btok[i1 * N_TOK + p1] = n; bwt[i1 * N_TOK + p1] = w1;
        atomicAdd(&usage[i0], w0);
        atomicAdd(&usage[i1], w1);
    }
}

__global__ __launch_bounds__(256) void expert_fb_kernel(
    const float* __restrict__ x, const float* __restrict__ W1,
    const float* __restrict__ b1, const float* __restrict__ W2,
    const float* __restrict__ b2, const int* __restrict__ cnt,
    const int* __restrict__ btok, const float* __restrict__ bwt,
    float* __restrict__ out)
{
    __shared__ float xs[TN][DIM];
    __shared__ float h1s[TN][HC];
    __shared__ int   tok_s[TN];
    __shared__ float wt_s[TN];
    int e = blockIdx.x >> 8;
    int tile = blockIdx.x & 255;
    int cn = cnt[e];
    int n0 = tile * TN;
    if (n0 >= cn) return;
    int nt = min(TN, cn - n0);
    int tid = threadIdx.x;
    if (tid < TN) {
        if (tid < nt) { tok_s[tid] = btok[e * N_TOK + n0 + tid]; wt_s[tid] = bwt[e * N_TOK + n0 + tid]; }
        else          { tok_s[tid] = 0; wt_s[tid] = 0.f; }
    }
    __syncthreads();
    for (int idx = tid; idx < TN * DIM; idx += 256) {
        int t = idx >> 9, d = idx & 511;
        xs[t][d] = (t < nt) ? x[tok_s[t] * DIM + d] : 0.f;
    }
    const float* W1e = W1 + (size_t)e * DIM * HID;
    const float* W2e = W2 + (size_t)e * HID * DIM;
    int tg = tid >> 6, lane = tid & 63;
    float oacc[4][8];
    {
        float4 ba = *(const float4*)&b2[e * DIM + lane * 8];
        float4 bb = *(const float4*)&b2[e * DIM + lane * 8 + 4];
#pragma unroll
        for (int ti = 0; ti < 4; ++ti) {
            oacc[ti][0] = ba.x; oacc[ti][1] = ba.y; oacc[ti][2] = ba.z; oacc[ti][3] = ba.w;
            oacc[ti][4] = bb.x; oacc[ti][5] = bb.y; oacc[ti][6] = bb.z; oacc[ti][7] = bb.w;
        }
    }
    __syncthreads();
    for (int ch = 0; ch < NCHUNK; ++ch) {
        int h0 = ch * HC;
        float f[4][4];
        {
            float4 b1v = *(const float4*)&b1[e * HID + h0 + lane * 4];
#pragma unroll
            for (int ti = 0; ti < 4; ++ti) {
                f[ti][0] = b1v.x; f[ti][1] = b1v.y; f[ti][2] = b1v.z; f[ti][3] = b1v.w;
            }
        }
        for (int d = 0; d < DIM; ++d) {
            float4 w1v = *(const float4*)&W1e[(size_t)d * HID + h0 + lane * 4];
#pragma unroll
            for (int ti = 0; ti < 4; ++ti) {
                float xv = xs[tg + 4 * ti][d];
                f[ti][0] += xv * w1v.x; f[ti][1] += xv * w1v.y;
                f[ti][2] += xv * w1v.z; f[ti][3] += xv * w1v.w;
            }
        }
        __syncthreads();
#pragma unroll
        for (int ti = 0; ti < 4; ++ti)
            *(float4*)&h1s[tg + 4 * ti][lane * 4] = make_float4(f[ti][0], f[ti][1], f[ti][2], f[ti][3]);
        __syncthreads();
        for (int j = 0; j < HC; ++j) {
            const float* w2row = &W2e[(size_t)(h0 + j) * DIM + lane * 8];
            float4 wa = *(const float4*)w2row;
            float4 wb = *(const float4*)(w2row + 4);
#pragma unroll
            for (int ti = 0; ti < 4; ++ti) {
                float hv = h1s[tg + 4 * ti][j];
                oacc[ti][0] += hv * wa.x; oacc[ti][1] += hv * wa.y;
                oacc[ti][2] += hv * wa.z; oacc[ti][3] += hv * wa.w;
                oacc[ti][4] += hv * wb.x; oacc[ti][5] += hv * wb.y;
                oacc[ti][6] += hv * wb.z; oacc[ti][7] += hv * wb.w;
            }
        }
    }
#pragma unroll
    for (int ti = 0; ti < 4; ++ti) {
        int t = tg + 4 * ti;
        if (t < nt) {
            float w = wt_s[t];
            float* o = &out[(size_t)tok_s[t] * DIM + lane * 8];
#pragma unroll
            for (int c = 0; c < 8; ++c)
                atomicAdd(&o[c], w * oacc[ti][c]);
        }
    }
}

// ------------------------------------------------------------------ host ----
extern "C" void kernel_launch(void* const* d_in, const int* in_sizes, int n_in,
                              void* d_out, int out_size, void* d_ws, size_t ws_size,
                              hipStream_t stream) {
    const float* x  = (const float*)d_in[0];
    const float* Wg = (const float*)d_in[1];
    const float* bg = (const float*)d_in[2];
    const float* W1 = (const float*)d_in[3];
    const float* b1 = (const float*)d_in[4];
    const float* W2 = (const float*)d_in[5];
    const float* b2 = (const float*)d_in[6];

    float* out   = (float*)d_out;
    float* usage = out + (size_t)N_TOK * DIM;

    // ws layout (bf16 path). O (gemm2 bf16 partials, 2*8192*512*2 = 16.8 MB)
    // aliases W1t: W1t dead after gemm1, same-stream ordering makes it safe.
    char* ws = (char*)d_ws;
    int*   cnt   = (int*)(ws + 0);
    int*   fill  = (int*)(ws + 32);
    int*   offs  = (int*)(ws + 64);
    int*   tb128 = (int*)(ws + 96);    // 9 ints
    int*   tb64  = (int*)(ws + 132);   // 9 ints
    int*   ntile = (int*)(ws + 168);   // [0]=n128, [1]=n64
    int*   te   = (int*)(ws + 256);       // expert pair, then slot map
    float* tw   = (float*)(ws + 33024);
    int*   btok = (int*)(ws + 65792);
    float* bwt  = (float*)(ws + 98560);
    unsigned short* Xb  = (unsigned short*)(ws + 131328);
    unsigned short* W1t = (unsigned short*)(ws + 4325632);
    unsigned short* O   = W1t;            // alias (see above)
    unsigned short* W2t = (unsigned short*)(ws + 21102848);
    unsigned short* H1  = (unsigned short*)(ws + 37880064);
    const size_t WS_NEED = 71434496ULL;

    if (ws_size >= WS_NEED) {
        hipMemsetAsync(cnt, 0, 32, stream);
        hipMemsetAsync(usage, 0, NEXP * sizeof(float), stream);  // combine overwrites combined
        transpose_cvt_kernel<<<dim3(DIM / 64, HID / 64, NEXP), 256, 0, stream>>>(W1, W1t, DIM, HID);
        transpose_cvt_kernel<<<dim3(HID / 64, DIM / 64, NEXP), 256, 0, stream>>>(W2, W2t, HID, DIM);
        gating_kernel<<<N_TOK / 16, 256, 0, stream>>>(x, Wg, bg, cnt, te, tw, usage, Xb);
        prefix_kernel<<<1, 64, 0, stream>>>(cnt, offs, fill, tb128, tb64, ntile);
        scatter_kernel<<<N_TOK / 256, 256, 0, stream>>>(te, tw, offs, fill, btok, bwt);
        gemm1_kernel<<<dim3(M1TILE, HID / 128), 256, 0, stream>>>(
            Xb, W1t, b1, cnt, offs, btok, tb128, ntile, H1);
        gemm2_kernel<<<dim3(M2TILE, DIM / 128, KSPLIT), 256, 0, stream>>>(
            H1, W2t, b2, cnt, offs, bwt, tb64, ntile, O);
        combine_kernel<<<N_TOK / 2, 256, 0, stream>>>(O, te, out);
    } else {
        // round-1 fp32 fallback (verified)
        int*   fcnt  = (int*)d_ws;
        int*   fbtok = (int*)((char*)d_ws + 256);
        float* fbwt  = (float*)((char*)d_ws + 256 + (size_t)NEXP * N_TOK * sizeof(int));
        hipMemsetAsync(d_out, 0, (size_t)(N_TOK * DIM + NEXP) * sizeof(float), stream);
        hipMemsetAsync(d_ws, 0, 256, stream);
        gating_fb_kernel<<<N_TOK / 4, 256, 0, stream>>>(x, Wg, bg, fcnt, fbtok, fbwt, usage);
        expert_fb_kernel<<<NEXP * (N_TOK / TN), 256, 0, stream>>>(
            x, W1, b1, W2, b2, fcnt, fbtok, fbwt, out);
    }
}

// Round 4
// 207.420 us; speedup vs baseline: 1.0467x; 1.0467x over previous
//
#include <hip/hip_runtime.h>
#include <hip/hip_bf16.h>

// MoE: N=4096 tokens, D=512, H=2048, E=8 experts, top-2.
// Round 12: amortization + dispatch-count attack.
// Round-11 post-mortem: counted-vmcnt was neutral (3rd schedule at ~40us per
// GEMM) -> schedule lever exhausted at this tile. Dispatch sum ~110us vs 217
// total: fixed overhead (launches + short K-runs) dominates.
//  - gemm2 KSPLIT=1: 32-step K-runs (2x amortization of prologue/epilogue),
//    grid 144x4=576 (~520 active, 2/CU), combine reads 2 partials not 4,
//    single bf16 rounding (more accurate, not less).
//  - transpose W1+W2 merged into ONE kernel (grid (256,16), shape from bid.y);
//    block (0,0) zeroes cnt/usage -> both hipMemsetAsyncs deleted.
//    bf16 path: 7 dispatches (was 10).
//  - gemm1 unchanged from round 11 (its best variant).
//  - XCD clustering, XOR swizzle (0 conflicts), tb-prefix tables,
//    O-aliasing-W1t, fallback path: unchanged.

#define N_TOK 4096
#define DIM   512
#define HID   2048
#define NEXP  8
#define TOTSLOT (2 * N_TOK)
#define M1TILE 72     // max 128-slot tiles (gemm1)
#define M2TILE 144    // max 64-slot tiles  (gemm2)

typedef __attribute__((ext_vector_type(8))) short short8;
typedef __attribute__((ext_vector_type(4))) float f32x4;

static __device__ __forceinline__ unsigned short f2bf(float f) {
    __hip_bfloat16 b = __float2bfloat16(f);
    return *reinterpret_cast<unsigned short*>(&b);
}
static __device__ __forceinline__ float bf2f(unsigned short u) {
    return __uint_as_float((unsigned)u << 16);
}

static __device__ __forceinline__ void load16_to_lds(const void* g, void* l) {
    __builtin_amdgcn_global_load_lds(
        (const __attribute__((address_space(1))) unsigned int*)g,
        (__attribute__((address_space(3))) unsigned int*)l, 16, 0, 0);
}

// ---------------------------------------------------------------- gating ----
__global__ __launch_bounds__(256) void gating_kernel(
    const float* __restrict__ x, const float* __restrict__ Wg,
    const float* __restrict__ bg,
    int* __restrict__ cnt, int* __restrict__ te, float* __restrict__ tw,
    float* __restrict__ usage, unsigned short* __restrict__ Xb)
{
    __shared__ int   lcnt[NEXP];
    __shared__ float lus[NEXP];
    int tid = threadIdx.x;
    if (tid < NEXP) { lcnt[tid] = 0; lus[tid] = 0.f; }
    __syncthreads();

    int wave = tid >> 6;
    int lane = tid & 63;

    for (int t = 0; t < 4; ++t) {
        int n = blockIdx.x * 16 + wave * 4 + t;

        float acc[NEXP];
#pragma unroll
        for (int e = 0; e < NEXP; ++e) acc[e] = 0.f;

#pragma unroll
        for (int it = 0; it < DIM / 64; ++it) {
            int d = it * 64 + lane;
            float xv = x[n * DIM + d];
            Xb[n * DIM + d] = f2bf(xv);
            float4 wa = *(const float4*)&Wg[d * NEXP];
            float4 wb = *(const float4*)&Wg[d * NEXP + 4];
            acc[0] += xv * wa.x; acc[1] += xv * wa.y;
            acc[2] += xv * wa.z; acc[3] += xv * wa.w;
            acc[4] += xv * wb.x; acc[5] += xv * wb.y;
            acc[6] += xv * wb.z; acc[7] += xv * wb.w;
        }
#pragma unroll
        for (int m = 32; m >= 1; m >>= 1) {
#pragma unroll
            for (int e = 0; e < NEXP; ++e)
                acc[e] += __shfl_xor(acc[e], m, 64);
        }
        if (lane == 0) {
            float l[NEXP];
#pragma unroll
            for (int e = 0; e < NEXP; ++e) l[e] = acc[e] + bg[e];
            int i0 = 0;
#pragma unroll
            for (int e = 1; e < NEXP; ++e) if (l[e] > l[i0]) i0 = e;
            int i1 = (i0 == 0) ? 1 : 0;
#pragma unroll
            for (int e = 0; e < NEXP; ++e)
                if (e != i0 && l[e] > l[i1]) i1 = e;
            float w0 = 1.f / (1.f + expf(l[i1] - l[i0]));
            float w1 = 1.f - w0;
            te[n * 2] = i0; te[n * 2 + 1] = i1;
            tw[n * 2] = w0; tw[n * 2 + 1] = w1;
            atomicAdd(&lcnt[i0], 1);
            atomicAdd(&lcnt[i1], 1);
            atomicAdd(&lus[i0], w0);
            atomicAdd(&lus[i1], w1);
        }
    }
    __syncthreads();
    if (tid < NEXP) {
        if (lcnt[tid]) atomicAdd(&cnt[tid], lcnt[tid]);
        if (lus[tid] != 0.f) atomicAdd(&usage[tid], lus[tid]);
    }
}

// tb128[e]/tb64[e]: first tile index of expert e at 128/64-slot granularity.
__global__ void prefix_kernel(const int* __restrict__ cnt,
                              int* __restrict__ offs, int* __restrict__ fill,
                              int* __restrict__ tb128, int* __restrict__ tb64,
                              int* __restrict__ ntile)
{
    if (threadIdx.x == 0) {
        int s = 0, a = 0, b = 0;
        for (int e = 0; e < NEXP; ++e) {
            offs[e] = s; s += cnt[e];
            tb128[e] = a; a += (cnt[e] + 127) >> 7;
            tb64[e]  = b; b += (cnt[e] + 63) >> 6;
        }
        tb128[NEXP] = a; tb64[NEXP] = b;
        ntile[0] = a; ntile[1] = b;
    }
    if (threadIdx.x < NEXP) fill[threadIdx.x] = 0;
}

__global__ __launch_bounds__(256) void scatter_kernel(
    int* __restrict__ te, const float* __restrict__ tw,
    const int* __restrict__ offs, int* __restrict__ fill,
    int* __restrict__ btok, float* __restrict__ bwt)
{
    __shared__ int lcnt[NEXP];
    __shared__ int gbase[NEXP];
    int tid = threadIdx.x;
    if (tid < NEXP) lcnt[tid] = 0;
    __syncthreads();
    int n = blockIdx.x * 256 + tid;
    int e0 = te[n * 2], e1 = te[n * 2 + 1];
    int l0 = atomicAdd(&lcnt[e0], 1);
    int l1 = atomicAdd(&lcnt[e1], 1);
    __syncthreads();
    if (tid < NEXP) gbase[tid] = atomicAdd(&fill[tid], lcnt[tid]);
    __syncthreads();
    int s0 = offs[e0] + gbase[e0] + l0;
    int s1 = offs[e1] + gbase[e1] + l1;
    btok[s0] = n; bwt[s0] = tw[n * 2];
    btok[s1] = n; bwt[s1] = tw[n * 2 + 1];
    te[n * 2] = s0; te[n * 2 + 1] = s1;   // slot map for combine
}

// Merged W1+W2 transpose/cvt: bid.y in [0,16): y<8 -> W1 expert y (R=DIM,
// C=HID, 8x32 tiles), y>=8 -> W2 expert y-8 (R=HID, C=DIM, 32x8 tiles).
// Block (0,0) also zeroes cnt/usage (stream-ordered before gating) --
// replaces two hipMemsetAsync dispatches.
__global__ __launch_bounds__(256) void transpose_cvt_kernel(
    const float* __restrict__ W1, const float* __restrict__ W2,
    unsigned short* __restrict__ W1t, unsigned short* __restrict__ W2t,
    int* __restrict__ cnt, float* __restrict__ usage)
{
    __shared__ unsigned short tile[64][65];
    int tid = threadIdx.x;
    int bx = blockIdx.x, z = blockIdx.y;
    if (bx == 0 && z == 0 && tid < NEXP) { cnt[tid] = 0; usage[tid] = 0.f; }

    const float* in; unsigned short* outp; int R, C, rt, ct, e;
    if (z < NEXP) { e = z;        in = W1; outp = W1t; R = DIM; C = HID; rt = bx >> 5; ct = bx & 31; }
    else          { e = z - NEXP; in = W2; outp = W2t; R = HID; C = DIM; rt = bx >> 3; ct = bx & 7;  }
    const float* src = in + (size_t)e * R * C;
    unsigned short* dst = outp + (size_t)e * R * C;
    int r0 = rt * 64, c0 = ct * 64;
    int rr = tid >> 2, cb = (tid & 3) * 16;
#pragma unroll
    for (int i = 0; i < 4; ++i) {
        float4 v = *(const float4*)&src[(size_t)(r0 + rr) * C + c0 + cb + i * 4];
        tile[rr][cb + i * 4 + 0] = f2bf(v.x);
        tile[rr][cb + i * 4 + 1] = f2bf(v.y);
        tile[rr][cb + i * 4 + 2] = f2bf(v.z);
        tile[rr][cb + i * 4 + 3] = f2bf(v.w);
    }
    __syncthreads();
#pragma unroll
    for (int i = 0; i < 4; ++i) {
        ushort4 u;
        u.x = tile[cb + i * 4 + 0][rr];
        u.y = tile[cb + i * 4 + 1][rr];
        u.z = tile[cb + i * 4 + 2][rr];
        u.w = tile[cb + i * 4 + 3][rr];
        *(ushort4*)&dst[(size_t)(c0 + rr) * R + r0 + cb + i * 4] = u;
    }
}

// ------------------------------------------------------------- MFMA GEMM ----
// LDS: rows x 64 bf16 per buffer, chunk c of row R at physical c^(R&7)
// (0 bank conflicts). Counted-vmcnt dbuf: stage(next) -> vmcnt(cur-done) ->
// raw barrier -> MFMA(cur) -> raw barrier. Prefetch stays in flight.

// gemm1: 128 tokens x 128 h per block. grid (72, 16).
__global__ __launch_bounds__(256) void gemm1_kernel(
    const unsigned short* __restrict__ Xb, const unsigned short* __restrict__ W1t,
    const float* __restrict__ b1, const int* __restrict__ cnt,
    const int* __restrict__ offs, const int* __restrict__ btok,
    const int* __restrict__ tb128, const int* __restrict__ ntile,
    unsigned short* __restrict__ H1)
{
    __shared__ __align__(16) unsigned short Ws[2][128 * 64];
    __shared__ __align__(16) unsigned short Xs[2][128 * 64];
    __shared__ int tok_s[128];

    int bx = blockIdx.x;
    int ti = (bx & 7) * (M1TILE / 8) + (bx >> 3);
    if (ti >= ntile[0]) return;
    int e = 0;
#pragma unroll
    for (int k = 1; k < NEXP; ++k) if (ti >= tb128[k]) e = k;
    int tt = ti - tb128[e];
    int ht = blockIdx.y;
    int cn = cnt[e];
    int off_e = offs[e];
    int tid = threadIdx.x;

    if (tid < 128) {
        int lr = tt * 128 + tid;
        tok_s[tid] = (lr < cn) ? btok[off_e + lr] : 0;
    }
    __syncthreads();   // tok_s read by staging

    int wave = tid >> 6, lane = tid & 63;
    int mbase = (wave >> 1) * 64, nbase = (wave & 1) * 64;
    int quad = lane >> 4, lcol = lane & 15;
    f32x4 acc[4][4];
#pragma unroll
    for (int mi = 0; mi < 4; ++mi)
#pragma unroll
        for (int ni = 0; ni < 4; ++ni)
            acc[mi][ni] = (f32x4){0.f, 0.f, 0.f, 0.f};

    int Rb = tid >> 3, pc = tid & 7;
    const unsigned short* Wsrc = W1t + ((size_t)e * HID + ht * 128) * DIM;

    auto stage = [&](int buf, int k0) {
#pragma unroll
        for (int p = 0; p < 4; ++p) {
            int R = Rb + p * 32;
            int c = pc ^ (R & 7);
            load16_to_lds(&Wsrc[(size_t)R * DIM + k0 + c * 8], &Ws[buf][R * 64 + pc * 8]);
            load16_to_lds(&Xb[(size_t)tok_s[R] * DIM + k0 + c * 8], &Xs[buf][R * 64 + pc * 8]);
        }
    };

    stage(0, 0);                       // 8 loads in flight

    const int NT = DIM / 64;           // 8
    for (int t = 0; t < NT; ++t) {
        int cur = t & 1;
        if (t + 1 < NT) {
            stage(cur ^ 1, (t + 1) * 64);              // +8 loads (<=16 out)
            asm volatile("s_waitcnt vmcnt(8)" ::: "memory");  // cur's 8 done
        } else {
            asm volatile("s_waitcnt vmcnt(0)" ::: "memory");
        }
        __builtin_amdgcn_s_barrier();                  // no implicit drain
        __builtin_amdgcn_sched_barrier(0);
#pragma unroll
        for (int h = 0; h < 2; ++h) {
            int cs = ((h * 4 + quad) ^ (lcol & 7)) * 8;
            short8 a[4], b[4];
#pragma unroll
            for (int i = 0; i < 4; ++i) {
                a[i] = *(const short8*)&Ws[cur][(mbase + i * 16 + lcol) * 64 + cs];
                b[i] = *(const short8*)&Xs[cur][(nbase + i * 16 + lcol) * 64 + cs];
            }
#pragma unroll
            for (int mi = 0; mi < 4; ++mi)
#pragma unroll
                for (int ni = 0; ni < 4; ++ni)
                    acc[mi][ni] = __builtin_amdgcn_mfma_f32_16x16x32_bf16(
                        a[mi], b[ni], acc[mi][ni], 0, 0, 0);
        }
        __builtin_amdgcn_sched_barrier(0);
        __builtin_amdgcn_s_barrier();                  // cur reads done
    }

    float4 bv[4];
#pragma unroll
    for (int mi = 0; mi < 4; ++mi)
        bv[mi] = *(const float4*)&b1[e * HID + ht * 128 + mbase + mi * 16 + quad * 4];
#pragma unroll
    for (int ni = 0; ni < 4; ++ni) {
        int tn = tt * 128 + nbase + ni * 16 + lcol;
        if (tn >= cn) continue;
        size_t srow = (size_t)(off_e + tn) * HID + ht * 128;
#pragma unroll
        for (int mi = 0; mi < 4; ++mi) {
            int hh = mbase + mi * 16 + quad * 4;
            ushort4 u;
            u.x = f2bf(acc[mi][ni][0] + bv[mi].x);
            u.y = f2bf(acc[mi][ni][1] + bv[mi].y);
            u.z = f2bf(acc[mi][ni][2] + bv[mi].z);
            u.w = f2bf(acc[mi][ni][3] + bv[mi].w);
            *(ushort4*)&H1[srow + hh] = u;
        }
    }
}

// gemm2: 64 slots x 128 d per block, FULL K (KSPLIT=1, 32 steps).
// grid (144, 4). Writes bf16 O[slot][d] = w*(acc + bias) -- plain stores.
// O aliases the W1t region (dead after gemm1; same stream).
__global__ __launch_bounds__(256) void gemm2_kernel(
    const unsigned short* __restrict__ H1, const unsigned short* __restrict__ W2t,
    const float* __restrict__ b2, const int* __restrict__ cnt,
    const int* __restrict__ offs, const float* __restrict__ bwt,
    const int* __restrict__ tb64, const int* __restrict__ ntile,
    unsigned short* __restrict__ O)
{
    __shared__ __align__(16) unsigned short Ws[2][128 * 64];   // d rows
    __shared__ __align__(16) unsigned short Hs[2][64 * 64];    // slot rows
    __shared__ float wt_s[64];

    int bx = blockIdx.x;
    int ti = (bx & 7) * (M2TILE / 8) + (bx >> 3);
    if (ti >= ntile[1]) return;
    int e = 0;
#pragma unroll
    for (int k = 1; k < NEXP; ++k) if (ti >= tb64[k]) e = k;
    int tt = ti - tb64[e];
    int dt = blockIdx.y;
    int cn = cnt[e];
    int off_e = offs[e];
    int sb = off_e + tt * 64;
    int tid = threadIdx.x;

    if (tid < 64) {
        int lr = tt * 64 + tid;
        wt_s[tid] = (lr < cn) ? bwt[off_e + lr] : 0.f;
    }

    int wave = tid >> 6, lane = tid & 63;
    int nbase = wave * 32;                 // d-offset of this wave within 128
    int quad = lane >> 4, lcol = lane & 15;
    f32x4 acc[4][2];
#pragma unroll
    for (int mi = 0; mi < 4; ++mi)
#pragma unroll
        for (int ni = 0; ni < 2; ++ni)
            acc[mi][ni] = (f32x4){0.f, 0.f, 0.f, 0.f};

    int Rb = tid >> 3, pc = tid & 7;
    const unsigned short* Wsrc = W2t + ((size_t)e * DIM + dt * 128) * HID;

    auto stage = [&](int buf, int k0) {
#pragma unroll
        for (int p = 0; p < 4; ++p) {      // Ws: 128 d-rows
            int R = Rb + p * 32;
            int c = pc ^ (R & 7);
            load16_to_lds(&Wsrc[(size_t)R * HID + k0 + c * 8], &Ws[buf][R * 64 + pc * 8]);
        }
#pragma unroll
        for (int p = 0; p < 2; ++p) {      // Hs: 64 slot-rows
            int R = Rb + p * 32;
            int c = pc ^ (R & 7);
            int sr = sb + R; if (sr > TOTSLOT - 1) sr = TOTSLOT - 1;
            load16_to_lds(&H1[(size_t)sr * HID + k0 + c * 8], &Hs[buf][R * 64 + pc * 8]);
        }
    };

    stage(0, 0);                           // 6 loads in flight

    const int NT = HID / 64;               // 32
    for (int t = 0; t < NT; ++t) {
        int cur = t & 1;
        if (t + 1 < NT) {
            stage(cur ^ 1, (t + 1) * 64);  // +6 loads (<=12 out)
            asm volatile("s_waitcnt vmcnt(6)" ::: "memory");  // cur's 6 done
        } else {
            asm volatile("s_waitcnt vmcnt(0)" ::: "memory");
        }
        __builtin_amdgcn_s_barrier();
        __builtin_amdgcn_sched_barrier(0);
#pragma unroll
        for (int h = 0; h < 2; ++h) {
            int cs = ((h * 4 + quad) ^ (lcol & 7)) * 8;
            short8 a[4], b[2];
#pragma unroll
            for (int i = 0; i < 4; ++i)
                a[i] = *(const short8*)&Hs[cur][(i * 16 + lcol) * 64 + cs];          // A = slots
#pragma unroll
            for (int i = 0; i < 2; ++i)
                b[i] = *(const short8*)&Ws[cur][(nbase + i * 16 + lcol) * 64 + cs];  // B = d
#pragma unroll
            for (int mi = 0; mi < 4; ++mi)
#pragma unroll
                for (int ni = 0; ni < 2; ++ni)
                    acc[mi][ni] = __builtin_amdgcn_mfma_f32_16x16x32_bf16(
                        a[mi], b[ni], acc[mi][ni], 0, 0, 0);
        }
        __builtin_amdgcn_sched_barrier(0);
        __builtin_amdgcn_s_barrier();
    }

    unsigned short* Oe = O + (size_t)sb * DIM + dt * 128;
#pragma unroll
    for (int ni = 0; ni < 2; ++ni) {
        int dl = nbase + ni * 16 + lcol;
        float bv = b2[e * DIM + dt * 128 + dl];
#pragma unroll
        for (int mi = 0; mi < 4; ++mi) {
            int rl = mi * 16 + quad * 4;
#pragma unroll
            for (int r = 0; r < 4; ++r) {
                int sl = rl + r;
                if (tt * 64 + sl < cn)
                    Oe[(size_t)sl * DIM + dl] = f2bf(wt_s[sl] * (acc[mi][ni][r] + bv));
            }
        }
    }
}

// out[n][d] = O[s0][d] + O[s1][d] (token's 2 slots; KSPLIT=1 -> 2 reads).
__global__ __launch_bounds__(256) void combine_kernel(
    const unsigned short* __restrict__ O, const int* __restrict__ sidx,
    float* __restrict__ out)
{
    int tid = threadIdx.x;
    int n = blockIdx.x * 2 + (tid >> 7);
    int dd = (tid & 127) * 4;
    int s0 = sidx[n * 2], s1 = sidx[n * 2 + 1];
    ushort4 a = *(const ushort4*)&O[(size_t)s0 * DIM + dd];
    ushort4 c = *(const ushort4*)&O[(size_t)s1 * DIM + dd];
    float4 o;
    o.x = bf2f(a.x) + bf2f(c.x);
    o.y = bf2f(a.y) + bf2f(c.y);
    o.z = bf2f(a.z) + bf2f(c.z);
    o.w = bf2f(a.w) + bf2f(c.w);
    *(float4*)&out[(size_t)n * DIM + dd] = o;
}

// ------------------------------------------------- round-1 fp32 fallback ----
#define TN 16
#define HC 256
#define NCHUNK (HID / HC)

__global__ __launch_bounds__(256) void gating_fb_kernel(
    const float* __restrict__ x, const float* __restrict__ Wg,
    const float* __restrict__ bg,
    int* __restrict__ cnt, int* __restrict__ btok, float* __restrict__ bwt,
    float* __restrict__ usage)
{
    int wave = threadIdx.x >> 6;
    int lane = threadIdx.x & 63;
    int n = blockIdx.x * 4 + wave;
    float acc[NEXP];
#pragma unroll
    for (int e = 0; e < NEXP; ++e) acc[e] = 0.f;
    for (int d = lane; d < DIM; d += 64) {
        float xv = x[n * DIM + d];
        float4 wa = *(const float4*)&Wg[d * NEXP];
        float4 wb = *(const float4*)&Wg[d * NEXP + 4];
        acc[0] += xv * wa.x; acc[1] += xv * wa.y;
        acc[2] += xv * wa.z; acc[3] += xv * wa.w;
        acc[4] += xv * wb.x; acc[5] += xv * wb.y;
        acc[6] += xv * wb.z; acc[7] += xv * wb.w;
    }
#pragma unroll
    for (int m = 32; m >= 1; m >>= 1)
#pragma unroll
        for (int e = 0; e < NEXP; ++e)
            acc[e] += __shfl_xor(acc[e], m, 64);
    if (lane == 0) {
        float l[NEXP];
#pragma unroll
        for (int e = 0; e < NEXP; ++e) l[e] = acc[e] + bg[e];
        int i0 = 0;
#pragma unroll
        for (int e = 1; e < NEXP; ++e) if (l[e] > l[i0]) i0 = e;
        int i1 = (i0 == 0) ? 1 : 0;
#pragma unroll
        for (int e = 0; e < NEXP; ++e)
            if (e != i0 && l[e] > l[i1]) i1 = e;
        float w0 = 1.f / (1.f + expf(l[i1] - l[i0]));
        float w1 = 1.f - w0;
        int p0 = atomicAdd(&cnt[i0], 1);
        btok[i0 * N_TOK + p0] = n; bwt[i0 * N_TOK + p0] = w0;
        int p1 = atomicAdd(&cnt[i1], 1);
        btok[i1 * N_TOK + p1] = n; bwt[i1 * N_TOK + p1] = w1;
        atomicAdd(&usage[i0], w0);
        atomicAdd(&usage[i1], w1);
    }
}

__global__ __launch_bounds__(256) void expert_fb_kernel(
    const float* __restrict__ x, const float* __restrict__ W1,
    const float* __restrict__ b1, const float* __restrict__ W2,
    const float* __restrict__ b2, const int* __restrict__ cnt,
    const int* __restrict__ btok, const float* __restrict__ bwt,
    float* __restrict__ out)
{
    __shared__ float xs[TN][DIM];
    __shared__ float h1s[TN][HC];
    __shared__ int   tok_s[TN];
    __shared__ float wt_s[TN];
    int e = blockIdx.x >> 8;
    int tile = blockIdx.x & 255;
    int cn = cnt[e];
    int n0 = tile * TN;
    if (n0 >= cn) return;
    int nt = min(TN, cn - n0);
    int tid = threadIdx.x;
    if (tid < TN) {
        if (tid < nt) { tok_s[tid] = btok[e * N_TOK + n0 + tid]; wt_s[tid] = bwt[e * N_TOK + n0 + tid]; }
        else          { tok_s[tid] = 0; wt_s[tid] = 0.f; }
    }
    __syncthreads();
    for (int idx = tid; idx < TN * DIM; idx += 256) {
        int t = idx >> 9, d = idx & 511;
        xs[t][d] = (t < nt) ? x[tok_s[t] * DIM + d] : 0.f;
    }
    const float* W1e = W1 + (size_t)e * DIM * HID;
    const float* W2e = W2 + (size_t)e * HID * DIM;
    int tg = tid >> 6, lane = tid & 63;
    float oacc[4][8];
    {
        float4 ba = *(const float4*)&b2[e * DIM + lane * 8];
        float4 bb = *(const float4*)&b2[e * DIM + lane * 8 + 4];
#pragma unroll
        for (int ti = 0; ti < 4; ++ti) {
            oacc[ti][0] = ba.x; oacc[ti][1] = ba.y; oacc[ti][2] = ba.z; oacc[ti][3] = ba.w;
            oacc[ti][4] = bb.x; oacc[ti][5] = bb.y; oacc[ti][6] = bb.z; oacc[ti][7] = bb.w;
        }
    }
    __syncthreads();
    for (int ch = 0; ch < NCHUNK; ++ch) {
        int h0 = ch * HC;
        float f[4][4];
        {
            float4 b1v = *(const float4*)&b1[e * HID + h0 + lane * 4];
#pragma unroll
            for (int ti = 0; ti < 4; ++ti) {
                f[ti][0] = b1v.x; f[ti][1] = b1v.y; f[ti][2] = b1v.z; f[ti][3] = b1v.w;
            }
        }
        for (int d = 0; d < DIM; ++d) {
            float4 w1v = *(const float4*)&W1e[(size_t)d * HID + h0 + lane * 4];
#pragma unroll
            for (int ti = 0; ti < 4; ++ti) {
                float xv = xs[tg + 4 * ti][d];
                f[ti][0] += xv * w1v.x; f[ti][1] += xv * w1v.y;
                f[ti][2] += xv * w1v.z; f[ti][3] += xv * w1v.w;
            }
        }
        __syncthreads();
#pragma unroll
        for (int ti = 0; ti < 4; ++ti)
            *(float4*)&h1s[tg + 4 * ti][lane * 4] = make_float4(f[ti][0], f[ti][1], f[ti][2], f[ti][3]);
        __syncthreads();
        for (int j = 0; j < HC; ++j) {
            const float* w2row = &W2e[(size_t)(h0 + j) * DIM + lane * 8];
            float4 wa = *(const float4*)w2row;
            float4 wb = *(const float4*)(w2row + 4);
#pragma unroll
            for (int ti = 0; ti < 4; ++ti) {
                float hv = h1s[tg + 4 * ti][j];
                oacc[ti][0] += hv * wa.x; oacc[ti][1] += hv * wa.y;
                oacc[ti][2] += hv * wa.z; oacc[ti][3] += hv * wa.w;
                oacc[ti][4] += hv * wb.x; oacc[ti][5] += hv * wb.y;
                oacc[ti][6] += hv * wb.z; oacc[ti][7] += hv * wb.w;
            }
        }
    }
#pragma unroll
    for (int ti = 0; ti < 4; ++ti) {
        int t = tg + 4 * ti;
        if (t < nt) {
            float w = wt_s[t];
            float* o = &out[(size_t)tok_s[t] * DIM + lane * 8];
#pragma unroll
            for (int c = 0; c < 8; ++c)
                atomicAdd(&o[c], w * oacc[ti][c]);
        }
    }
}

// ------------------------------------------------------------------ host ----
extern "C" void kernel_launch(void* const* d_in, const int* in_sizes, int n_in,
                              void* d_out, int out_size, void* d_ws, size_t ws_size,
                              hipStream_t stream) {
    const float* x  = (const float*)d_in[0];
    const float* Wg = (const float*)d_in[1];
    const float* bg = (const float*)d_in[2];
    const float* W1 = (const float*)d_in[3];
    const float* b1 = (const float*)d_in[4];
    const float* W2 = (const float*)d_in[5];
    const float* b2 = (const float*)d_in[6];

    float* out   = (float*)d_out;
    float* usage = out + (size_t)N_TOK * DIM;

    // ws layout (bf16 path). O (gemm2 bf16 output, 8192*512*2 = 8.4 MB)
    // aliases W1t: W1t dead after gemm1, same-stream ordering makes it safe.
    char* ws = (char*)d_ws;
    int*   cnt   = (int*)(ws + 0);
    int*   fill  = (int*)(ws + 32);
    int*   offs  = (int*)(ws + 64);
    int*   tb128 = (int*)(ws + 96);    // 9 ints
    int*   tb64  = (int*)(ws + 132);   // 9 ints
    int*   ntile = (int*)(ws + 168);   // [0]=n128, [1]=n64
    int*   te   = (int*)(ws + 256);       // expert pair, then slot map
    float* tw   = (float*)(ws + 33024);
    int*   btok = (int*)(ws + 65792);
    float* bwt  = (float*)(ws + 98560);
    unsigned short* Xb  = (unsigned short*)(ws + 131328);
    unsigned short* W1t = (unsigned short*)(ws + 4325632);
    unsigned short* O   = W1t;            // alias (see above)
    unsigned short* W2t = (unsigned short*)(ws + 21102848);
    unsigned short* H1  = (unsigned short*)(ws + 37880064);
    const size_t WS_NEED = 71434496ULL;

    if (ws_size >= WS_NEED) {
        // 7 dispatches, no memsets (transpose block (0,0) zeroes cnt/usage).
        transpose_cvt_kernel<<<dim3(256, 16), 256, 0, stream>>>(W1, W2, W1t, W2t, cnt, usage);
        gating_kernel<<<N_TOK / 16, 256, 0, stream>>>(x, Wg, bg, cnt, te, tw, usage, Xb);
        prefix_kernel<<<1, 64, 0, stream>>>(cnt, offs, fill, tb128, tb64, ntile);
        scatter_kernel<<<N_TOK / 256, 256, 0, stream>>>(te, tw, offs, fill, btok, bwt);
        gemm1_kernel<<<dim3(M1TILE, HID / 128), 256, 0, stream>>>(
            Xb, W1t, b1, cnt, offs, btok, tb128, ntile, H1);
        gemm2_kernel<<<dim3(M2TILE, DIM / 128), 256, 0, stream>>>(
            H1, W2t, b2, cnt, offs, bwt, tb64, ntile, O);
        combine_kernel<<<N_TOK / 2, 256, 0, stream>>>(O, te, out);
    } else {
        // round-1 fp32 fallback (verified)
        int*   fcnt  = (int*)d_ws;
        int*   fbtok = (int*)((char*)d_ws + 256);
        float* fbwt  = (float*)((char*)d_ws + 256 + (size_t)NEXP * N_TOK * sizeof(int));
        hipMemsetAsync(d_out, 0, (size_t)(N_TOK * DIM + NEXP) * sizeof(float), stream);
        hipMemsetAsync(d_ws, 0, 256, stream);
        gating_fb_kernel<<<N_TOK / 4, 256, 0, stream>>>(x, Wg, bg, fcnt, fbtok, fbwt, usage);
        expert_fb_kernel<<<NEXP * (N_TOK / TN), 256, 0, stream>>>(
            x, W1, b1, W2, b2, fcnt, fbtok, fbwt, out);
    }
}